// Round 1
// baseline (421.129 us; speedup 1.0000x reference)
//
#include <hip/hip_runtime.h>

#define B_  4
#define C_  256
#define C8_ 32
#define N_  16384

__device__ __forceinline__ void fma4(float4& a, const float4& m, float s) {
  a.x += m.x * s; a.y += m.y * s; a.z += m.z * s; a.w += m.w * s;
}

// K1: klog[b][o][n] = sum_c Wk[o][c]*x[b][c][n] + bk[o]
// grid 128 = B * (N/512), block 256; each thread owns 2 n's, all 32 o's.
__global__ __launch_bounds__(256) void k1_klog(const float* __restrict__ x,
                                               const float* __restrict__ Wk,
                                               const float* __restrict__ bk,
                                               float* __restrict__ klog) {
  __shared__ float wkT[C_ * C8_];  // [c][o], 32 KiB, rows 128B-aligned for b128 broadcast reads
  const int t = threadIdx.x;
  const int b = blockIdx.x >> 5;
  const int n0 = (blockIdx.x & 31) * 512;
  for (int s = 0; s < 32; ++s) {
    int f = s * 256 + t;
    int o = f >> 8, c = f & 255;
    wkT[c * C8_ + o] = Wk[f];
  }
  __syncthreads();
  float acc0[C8_], acc1[C8_];
#pragma unroll
  for (int o = 0; o < C8_; ++o) { acc0[o] = 0.f; acc1[o] = 0.f; }
  const float* xb = x + (size_t)b * C_ * N_ + n0 + t;
  for (int c = 0; c < C_; ++c) {
    float xv0 = xb[(size_t)c * N_];
    float xv1 = xb[(size_t)c * N_ + 256];
    const float4* wrow = (const float4*)&wkT[c * C8_];
#pragma unroll
    for (int o8 = 0; o8 < 8; ++o8) {
      float4 w = wrow[o8];
      acc0[o8 * 4 + 0] += w.x * xv0; acc1[o8 * 4 + 0] += w.x * xv1;
      acc0[o8 * 4 + 1] += w.y * xv0; acc1[o8 * 4 + 1] += w.y * xv1;
      acc0[o8 * 4 + 2] += w.z * xv0; acc1[o8 * 4 + 2] += w.z * xv1;
      acc0[o8 * 4 + 3] += w.w * xv0; acc1[o8 * 4 + 3] += w.w * xv1;
    }
  }
  float* kout = klog + (size_t)(b * C8_) * N_ + n0 + t;
#pragma unroll
  for (int o = 0; o < C8_; ++o) {
    float bo = bk[o];
    kout[(size_t)o * N_] = acc0[o] + bo;
    kout[(size_t)o * N_ + 256] = acc1[o] + bo;
  }
}

// K2: per-row (b*32+o) softmax stats over N. grid 128, block 256.
__global__ __launch_bounds__(256) void k2_stats(const float* __restrict__ klog,
                                                float* __restrict__ rowmax,
                                                float* __restrict__ rowinv) {
  const int row = blockIdx.x;
  const int t = threadIdx.x;
  const float* p = klog + (size_t)row * N_;
  float m = -3.0e38f;
  for (int s = 0; s < N_ / 256; ++s) m = fmaxf(m, p[s * 256 + t]);
#pragma unroll
  for (int off = 32; off > 0; off >>= 1) m = fmaxf(m, __shfl_down(m, off));
  __shared__ float wred[4];
  __shared__ float sh_m;
  if ((t & 63) == 0) wred[t >> 6] = m;
  __syncthreads();
  if (t == 0) sh_m = fmaxf(fmaxf(wred[0], wred[1]), fmaxf(wred[2], wred[3]));
  __syncthreads();
  const float mx = sh_m;
  float sum = 0.f;
  for (int s = 0; s < N_ / 256; ++s) sum += __expf(p[s * 256 + t] - mx);
#pragma unroll
  for (int off = 32; off > 0; off >>= 1) sum += __shfl_down(sum, off);
  if ((t & 63) == 0) wred[t >> 6] = sum;
  __syncthreads();
  if (t == 0) {
    rowmax[row] = mx;
    rowinv[row] = 1.0f / (wred[0] + wred[1] + wred[2] + wred[3]);
  }
}

// K3: partial kx[b][o][c] = sum_{n in chunk} softmax(k)[b][o][n] * x[b][c][n]
// grid 128 = B * 32 chunks of 512 n. Register tile: 4 o x 8 c per thread.
__global__ __launch_bounds__(256) void k3_kxp(const float* __restrict__ x,
                                              const float* __restrict__ klog,
                                              const float* __restrict__ rowmax,
                                              const float* __restrict__ rowinv,
                                              float* __restrict__ kxp) {
  __shared__ float kT[32 * 36];    // [j][o], stride 36 keeps float4 16B-aligned
  __shared__ float xl[256 * 33];   // [c][j], stride 33 breaks the stride-32 bank pattern
  const int t = threadIdx.x;
  const int b = blockIdx.x >> 5;
  const int n0 = (blockIdx.x & 31) * 512;
  const int oy = t >> 5;  // 0..7 -> o = oy*4+oo
  const int cx = t & 31;  // c = cx + 32*i
  float acc[4][8];
#pragma unroll
  for (int oo = 0; oo < 4; ++oo)
#pragma unroll
    for (int i = 0; i < 8; ++i) acc[oo][i] = 0.f;

  for (int ns = 0; ns < 16; ++ns) {
    const int nb = n0 + ns * 32;
#pragma unroll
    for (int s = 0; s < 4; ++s) {
      int f = s * 256 + t;
      int o = f >> 5, j = f & 31;
      int row = b * C8_ + o;
      float v = klog[(size_t)row * N_ + nb + j];
      kT[j * 36 + o] = __expf(v - rowmax[row]) * rowinv[row];
    }
#pragma unroll
    for (int rr = 0; rr < 32; ++rr) {
      int c = rr * 8 + (t >> 5);
      int j = t & 31;
      xl[c * 33 + j] = x[(size_t)(b * C_ + c) * N_ + nb + j];
    }
    __syncthreads();
    for (int j = 0; j < 32; ++j) {
      float4 k4 = *(const float4*)&kT[j * 36 + oy * 4];
#pragma unroll
      for (int i = 0; i < 8; ++i) {
        float xv = xl[(cx + 32 * i) * 33 + j];
        acc[0][i] += k4.x * xv;
        acc[1][i] += k4.y * xv;
        acc[2][i] += k4.z * xv;
        acc[3][i] += k4.w * xv;
      }
    }
    __syncthreads();
  }
  float* dst = kxp + (size_t)blockIdx.x * (C8_ * C_);
#pragma unroll
  for (int oo = 0; oo < 4; ++oo)
#pragma unroll
    for (int i = 0; i < 8; ++i)
      dst[(oy * 4 + oo) * C_ + cx + 32 * i] = acc[oo][i];
}

// K3b: reduce 32 chunk-partials per batch. grid 128 = B*32(o), block 256(c).
__global__ __launch_bounds__(256) void k3b_reduce(const float* __restrict__ kxp,
                                                  float* __restrict__ kx) {
  const int t = threadIdx.x;
  const int b = blockIdx.x >> 5;
  const int o = blockIdx.x & 31;
  float s = 0.f;
  for (int ch = 0; ch < 32; ++ch)
    s += kxp[(size_t)(b * 32 + ch) * (C8_ * C_) + o * C_ + t];
  kx[(size_t)(b * C8_ + o) * C_ + t] = s;
}

// K4a: kv[b][o][c] = sum_c' Wv[c][c'] * kx[b][o][c'] + bv[c]. grid 128 = b*o, thread = c.
__global__ __launch_bounds__(256) void k4a_kv(const float* __restrict__ Wv,
                                              const float* __restrict__ bv,
                                              const float* __restrict__ kx,
                                              float* __restrict__ kv) {
  __shared__ float kxl[C_];
  const int t = threadIdx.x;
  const int bo = blockIdx.x;
  kxl[t] = kx[(size_t)bo * C_ + t];
  __syncthreads();
  const float4* wr = (const float4*)&Wv[(size_t)t * C_];
  float s = 0.f;
#pragma unroll 8
  for (int c4 = 0; c4 < 64; ++c4) {
    float4 w = wr[c4];
    float4 k4 = *(const float4*)&kxl[c4 * 4];
    s += w.x * k4.x + w.y * k4.y + w.z * k4.z + w.w * k4.w;
  }
  kv[(size_t)bo * C_ + t] = s + bv[t];
}

// K4b: M[b][c''][c] = sum_o Wq[o][c'']*kv[b][o][c];  r[b][c] = sum_o bq[o]*kv[b][o][c]
// grid 64 = B*16 groups of 16 c'' rows, thread = c.
__global__ __launch_bounds__(256) void k4b_M(const float* __restrict__ Wq,
                                             const float* __restrict__ bq,
                                             const float* __restrict__ kv,
                                             float* __restrict__ Mm,
                                             float* __restrict__ r) {
  __shared__ float kvl[C8_ * C_];  // 32 KiB
  __shared__ float wqT[16 * C8_];  // [i][o]
  const int t = threadIdx.x;
  const int b = blockIdx.x >> 4;
  const int c0 = (blockIdx.x & 15) * 16;
  for (int s = 0; s < 32; ++s)
    kvl[s * 256 + t] = kv[(size_t)b * C8_ * C_ + s * 256 + t];
#pragma unroll
  for (int s = 0; s < 2; ++s) {
    int f = s * 256 + t;
    int o = f >> 4, i = f & 15;
    wqT[i * C8_ + o] = Wq[o * C_ + c0 + i];
  }
  __syncthreads();
  float kvreg[C8_];
#pragma unroll
  for (int o = 0; o < C8_; ++o) kvreg[o] = kvl[o * C_ + t];
  for (int i = 0; i < 16; ++i) {
    const float4* w4 = (const float4*)&wqT[i * C8_];
    float s = 0.f;
#pragma unroll
    for (int o8 = 0; o8 < 8; ++o8) {
      float4 w = w4[o8];
      s += w.x * kvreg[o8 * 4] + w.y * kvreg[o8 * 4 + 1] +
           w.z * kvreg[o8 * 4 + 2] + w.w * kvreg[o8 * 4 + 3];
    }
    Mm[(size_t)(b * C_ + c0 + i) * C_ + t] = s;
  }
  if (c0 == 0) {
    float rr = 0.f;
#pragma unroll
    for (int o = 0; o < C8_; ++o) rr += bq[o] * kvreg[o];
    r[b * C_ + t] = rr;
  }
}

// K5: out[b][n'*256+c2] = gamma*( sum_c'' x[b][c''][n']*M[b][c''][c2] + r[b][c2] ) + x[b][n'*256+c2]
// grid 1024 = B * (N/64), block 256 as 16(tx: c2) x 16(ty: n'), 4x16 register tile.
__global__ __launch_bounds__(256) void k5_out(const float* __restrict__ x,
                                              const float* __restrict__ Mm,
                                              const float* __restrict__ r,
                                              const float* __restrict__ gamma_p,
                                              float* __restrict__ out) {
  __shared__ float xc[32 * 64];    // [kk][n'loc] 8 KiB
  __shared__ float mc[32 * 256];   // [kk][c2]   32 KiB
  const int t = threadIdx.x;
  const int b = blockIdx.x >> 8;
  const int n0 = (blockIdx.x & 255) * 64;
  const int tx = t & 15;  // c2 = tx*4 + g*64
  const int ty = t >> 4;  // n'loc = ty*4 + i
  float4 acc[4][4];
#pragma unroll
  for (int i = 0; i < 4; ++i)
#pragma unroll
    for (int g = 0; g < 4; ++g) acc[i][g] = make_float4(0.f, 0.f, 0.f, 0.f);

  for (int cc = 0; cc < 8; ++cc) {
#pragma unroll
    for (int rr = 0; rr < 8; ++rr) {
      int kk = rr * 4 + (t >> 6);
      int j = t & 63;
      xc[kk * 64 + j] = x[(size_t)(b * C_ + cc * 32 + kk) * N_ + n0 + j];
    }
#pragma unroll
    for (int s = 0; s < 32; ++s)
      mc[s * 256 + t] = Mm[(size_t)(b * C_ + cc * 32 + s) * C_ + t];
    __syncthreads();
    for (int kk = 0; kk < 32; ++kk) {
      float4 xv = *(const float4*)&xc[kk * 64 + ty * 4];
      const float4* mrow = (const float4*)&mc[kk * 256];
      float4 m0 = mrow[tx];
      float4 m1 = mrow[tx + 16];
      float4 m2 = mrow[tx + 32];
      float4 m3 = mrow[tx + 48];
      fma4(acc[0][0], m0, xv.x); fma4(acc[0][1], m1, xv.x); fma4(acc[0][2], m2, xv.x); fma4(acc[0][3], m3, xv.x);
      fma4(acc[1][0], m0, xv.y); fma4(acc[1][1], m1, xv.y); fma4(acc[1][2], m2, xv.y); fma4(acc[1][3], m3, xv.y);
      fma4(acc[2][0], m0, xv.z); fma4(acc[2][1], m1, xv.z); fma4(acc[2][2], m2, xv.z); fma4(acc[2][3], m3, xv.z);
      fma4(acc[3][0], m0, xv.w); fma4(acc[3][1], m1, xv.w); fma4(acc[3][2], m2, xv.w); fma4(acc[3][3], m3, xv.w);
    }
    __syncthreads();
  }
  const float g = gamma_p[0];
  float4 rv[4];
#pragma unroll
  for (int gg = 0; gg < 4; ++gg)
    rv[gg] = *(const float4*)&r[b * C_ + tx * 4 + gg * 64];
#pragma unroll
  for (int i = 0; i < 4; ++i) {
    size_t base = (size_t)b * C_ * N_ + (size_t)(n0 + ty * 4 + i) * 256 + tx * 4;
#pragma unroll
    for (int gg = 0; gg < 4; ++gg) {
      float4 xr = *(const float4*)&x[base + gg * 64];
      float4 v;
      v.x = g * (acc[i][gg].x + rv[gg].x) + xr.x;
      v.y = g * (acc[i][gg].y + rv[gg].y) + xr.y;
      v.z = g * (acc[i][gg].z + rv[gg].z) + xr.z;
      v.w = g * (acc[i][gg].w + rv[gg].w) + xr.w;
      *(float4*)&out[base + gg * 64] = v;
    }
  }
}

extern "C" void kernel_launch(void* const* d_in, const int* in_sizes, int n_in,
                              void* d_out, int out_size, void* d_ws, size_t ws_size,
                              hipStream_t stream) {
  const float* x  = (const float*)d_in[0];
  const float* Wq = (const float*)d_in[1];
  const float* bq = (const float*)d_in[2];
  const float* Wk = (const float*)d_in[3];
  const float* bk = (const float*)d_in[4];
  const float* Wv = (const float*)d_in[5];
  const float* bv = (const float*)d_in[6];
  const float* gm = (const float*)d_in[7];
  float* out = (float*)d_out;

  float* ws     = (float*)d_ws;
  float* klog   = ws;                                   // B*32*N   = 2097152
  float* rowmax = klog + (size_t)B_ * C8_ * N_;         // 128
  float* rowinv = rowmax + 128;                         // 128
  float* kxp    = rowinv + 128;                         // 128*8192 = 1048576
  float* kx     = kxp + 128 * (size_t)(C8_ * C_);       // 32768
  float* kv     = kx + (size_t)B_ * C8_ * C_;           // 32768
  float* Mm     = kv + (size_t)B_ * C8_ * C_;           // 262144
  float* r      = Mm + (size_t)B_ * C_ * C_;            // 1024

  k1_klog   <<<128,  256, 0, stream>>>(x, Wk, bk, klog);
  k2_stats  <<<128,  256, 0, stream>>>(klog, rowmax, rowinv);
  k3_kxp    <<<128,  256, 0, stream>>>(x, klog, rowmax, rowinv, kxp);
  k3b_reduce<<<128,  256, 0, stream>>>(kxp, kx);
  k4a_kv    <<<128,  256, 0, stream>>>(Wv, bv, kx, kv);
  k4b_M     <<<64,   256, 0, stream>>>(Wq, bq, kv, Mm, r);
  k5_out    <<<1024, 256, 0, stream>>>(x, Mm, r, gm, out);
}

// Round 2
// 281.171 us; speedup vs baseline: 1.4978x; 1.4978x over previous
//
#include <hip/hip_runtime.h>
#include <hip/hip_bf16.h>

#define B_  4
#define C_  256
#define C8_ 32
#define N_  16384

typedef unsigned short ushort_t;
typedef __attribute__((ext_vector_type(8))) short short8;
typedef __attribute__((ext_vector_type(4))) float floatx4;

__device__ __forceinline__ short bf16_rne(float f) {
  unsigned u = __float_as_uint(f);
  u += 0x7fffu + ((u >> 16) & 1u);
  return (short)(u >> 16);
}

__device__ __forceinline__ short8 pack8(float f0, float f1, float f2, float f3,
                                        float f4, float f5, float f6, float f7) {
  union { short8 s; __hip_bfloat162 h[4]; } u;
  u.h[0] = __float22bfloat162_rn(make_float2(f0, f1));
  u.h[1] = __float22bfloat162_rn(make_float2(f2, f3));
  u.h[2] = __float22bfloat162_rn(make_float2(f4, f5));
  u.h[3] = __float22bfloat162_rn(make_float2(f6, f7));
  return u.s;
}

// K0: zero den accumulator; cast Wk -> bf16 (A-operand of K1). grid 32 x 256.
__global__ __launch_bounds__(256) void k0_init(const float* __restrict__ Wk,
                                               ushort_t* __restrict__ Wkb,
                                               float* __restrict__ den) {
  const int i = blockIdx.x * 256 + threadIdx.x;  // 0..8191
  Wkb[i] = (ushort_t)bf16_rne(Wk[i]);
  if (i < 128) den[i] = 0.f;
}

// K1: p[b][o][n] = exp( (Wk . x)[o][n] + bk[o] )   (no max-subtraction: |klog|<~6)
// plus den[b][o] += sum_n p via atomics. MFMA 16x16x32 bf16.
// grid = B*128 (n-chunks of 128), block 256 = 4 waves; wave w: n-sub 32, both m-tiles.
__global__ __launch_bounds__(256) void k1_p(const float* __restrict__ x,
                                            const ushort_t* __restrict__ Wkb,
                                            const float* __restrict__ bk,
                                            ushort_t* __restrict__ p,
                                            float* __restrict__ den) {
  const int t = threadIdx.x;
  const int lane = t & 63;
  const int w = t >> 6;
  const int b = blockIdx.x >> 7;
  const int n0 = (blockIdx.x & 127) * 128 + w * 32;
  const int l15 = lane & 15, l4 = lane >> 4;
  const floatx4 z = {0.f, 0.f, 0.f, 0.f};
  floatx4 acc[2][2];
  acc[0][0] = z; acc[0][1] = z; acc[1][0] = z; acc[1][1] = z;

  for (int kc = 0; kc < 8; ++kc) {
    const int kb = kc * 32 + l4 * 8;  // k = c'' base for this lane-quad
    short8 a0 = *(const short8*)&Wkb[l15 * C_ + kb];
    short8 a1 = *(const short8*)&Wkb[(16 + l15) * C_ + kb];
#pragma unroll
    for (int nt = 0; nt < 2; ++nt) {
      const int n = n0 + nt * 16 + l15;
      const float* xp = x + (size_t)(b * C_ + kb) * N_ + n;
      short8 bf = pack8(xp[0], xp[(size_t)N_], xp[2 * (size_t)N_], xp[3 * (size_t)N_],
                        xp[4 * (size_t)N_], xp[5 * (size_t)N_], xp[6 * (size_t)N_],
                        xp[7 * (size_t)N_]);
      acc[0][nt] = __builtin_amdgcn_mfma_f32_16x16x32_bf16(a0, bf, acc[0][nt], 0, 0, 0);
      acc[1][nt] = __builtin_amdgcn_mfma_f32_16x16x32_bf16(a1, bf, acc[1][nt], 0, 0, 0);
    }
  }
#pragma unroll
  for (int mt = 0; mt < 2; ++mt) {
    float ds[4] = {0.f, 0.f, 0.f, 0.f};
#pragma unroll
    for (int nt = 0; nt < 2; ++nt) {
#pragma unroll
      for (int rg = 0; rg < 4; ++rg) {
        const int o = mt * 16 + l4 * 4 + rg;   // D row
        const int n = n0 + nt * 16 + l15;      // D col
        float pe = __expf(acc[mt][nt][rg] + bk[o]);
        p[(size_t)(b * C8_ + o) * N_ + n] = (ushort_t)bf16_rne(pe);
        ds[rg] += pe;
      }
    }
#pragma unroll
    for (int rg = 0; rg < 4; ++rg) {
      float s = ds[rg];
      s += __shfl_xor(s, 1); s += __shfl_xor(s, 2);
      s += __shfl_xor(s, 4); s += __shfl_xor(s, 8);
      if (l15 == 0) atomicAdd(&den[b * C8_ + mt * 16 + l4 * 4 + rg], s);
    }
  }
}

// K3: split-K partials kxp[b][ch][o][c] = sum_{n in 256-chunk} p[o][n] * x[c][n]
// A = p (bf16 direct), B = x rows (float4 -> pk-cvt). grid = B*64, block 256.
__global__ __launch_bounds__(256) void k3_kxp(const float* __restrict__ x,
                                              const ushort_t* __restrict__ p,
                                              float* __restrict__ kxp) {
  const int t = threadIdx.x;
  const int lane = t & 63;
  const int w = t >> 6;
  const int b = blockIdx.x >> 6;
  const int ch = blockIdx.x & 63;
  const int l15 = lane & 15, l4 = lane >> 4;
  const int mt = w & 1;            // o-halves
  const int c0 = (w >> 1) * 128;   // c-halves
  const int nch = ch * 256;
  const floatx4 z = {0.f, 0.f, 0.f, 0.f};
  floatx4 acc[8];
#pragma unroll
  for (int i = 0; i < 8; ++i) acc[i] = z;

  for (int kc = 0; kc < 8; ++kc) {
    const int kn = nch + kc * 32 + l4 * 8;
    short8 a = *(const short8*)&p[(size_t)(b * C8_ + mt * 16 + l15) * N_ + kn];
#pragma unroll
    for (int ct = 0; ct < 8; ++ct) {
      const float* xp = x + (size_t)(b * C_ + c0 + ct * 16 + l15) * N_ + kn;
      float4 xa = *(const float4*)xp;
      float4 xb = *(const float4*)(xp + 4);
      short8 bf = pack8(xa.x, xa.y, xa.z, xa.w, xb.x, xb.y, xb.z, xb.w);
      acc[ct] = __builtin_amdgcn_mfma_f32_16x16x32_bf16(a, bf, acc[ct], 0, 0, 0);
    }
  }
#pragma unroll
  for (int ct = 0; ct < 8; ++ct) {
#pragma unroll
    for (int rg = 0; rg < 4; ++rg) {
      const int o = mt * 16 + l4 * 4 + rg;
      kxp[((size_t)(b * 64 + ch) * C8_ + o) * C_ + c0 + ct * 16 + l15] = acc[ct][rg];
    }
  }
}

// k3b: kx[b][o][c] = (sum_ch kxp) / den[b][o]. grid 128 = B*32(o), block 256(c).
__global__ __launch_bounds__(256) void k3b_reduce(const float* __restrict__ kxp,
                                                  const float* __restrict__ den,
                                                  float* __restrict__ kx) {
  const int t = threadIdx.x;
  const int b = blockIdx.x >> 5;
  const int o = blockIdx.x & 31;
  float s = 0.f;
  for (int ch = 0; ch < 64; ++ch)
    s += kxp[((size_t)(b * 64 + ch) * C8_ + o) * C_ + t];
  kx[(size_t)(b * C8_ + o) * C_ + t] = s / den[b * C8_ + o];
}

// K4a: kv[b][o][c] = sum_c' Wv[c][c'] * kx[b][o][c'] + bv[c]. grid 128, thread = c.
__global__ __launch_bounds__(256) void k4a_kv(const float* __restrict__ Wv,
                                              const float* __restrict__ bv,
                                              const float* __restrict__ kx,
                                              float* __restrict__ kv) {
  __shared__ float kxl[C_];
  const int t = threadIdx.x;
  const int bo = blockIdx.x;
  kxl[t] = kx[(size_t)bo * C_ + t];
  __syncthreads();
  const float4* wr = (const float4*)&Wv[(size_t)t * C_];
  float s = 0.f;
#pragma unroll 8
  for (int c4 = 0; c4 < 64; ++c4) {
    float4 wv = wr[c4];
    float4 k4 = *(const float4*)&kxl[c4 * 4];
    s += wv.x * k4.x + wv.y * k4.y + wv.z * k4.z + wv.w * k4.w;
  }
  kv[(size_t)bo * C_ + t] = s + bv[t];
}

// K4b: Mt[b][c][c''] = bf16( sum_o Wq[o][c'']*kv[b][o][c] )  (stored TRANSPOSED, bf16,
// as K5's B operand); r[b][c] = sum_o bq[o]*kv[b][o][c]. grid 64, block 256.
__global__ __launch_bounds__(256) void k4b_M(const float* __restrict__ Wq,
                                             const float* __restrict__ bq,
                                             const float* __restrict__ kv,
                                             ushort_t* __restrict__ Mt,
                                             float* __restrict__ r) {
  __shared__ float kvl[C8_ * C_];
  __shared__ float wqT[16 * C8_];
  const int t = threadIdx.x;
  const int b = blockIdx.x >> 4;
  const int c0 = (blockIdx.x & 15) * 16;
  for (int s = 0; s < 32; ++s)
    kvl[s * 256 + t] = kv[(size_t)b * C8_ * C_ + s * 256 + t];
#pragma unroll
  for (int s = 0; s < 2; ++s) {
    int f = s * 256 + t;
    int o = f >> 4, i = f & 15;
    wqT[i * C8_ + o] = Wq[o * C_ + c0 + i];
  }
  __syncthreads();
  float kvreg[C8_];
#pragma unroll
  for (int o = 0; o < C8_; ++o) kvreg[o] = kvl[o * C_ + t];
  for (int i = 0; i < 16; ++i) {
    const float4* w4 = (const float4*)&wqT[i * C8_];
    float s = 0.f;
#pragma unroll
    for (int o8 = 0; o8 < 8; ++o8) {
      float4 wv = w4[o8];
      s += wv.x * kvreg[o8 * 4] + wv.y * kvreg[o8 * 4 + 1] +
           wv.z * kvreg[o8 * 4 + 2] + wv.w * kvreg[o8 * 4 + 3];
    }
    Mt[(size_t)(b * C_ + t) * C_ + c0 + i] = (ushort_t)bf16_rne(s);
  }
  if (c0 == 0) {
    float rr = 0.f;
#pragma unroll
    for (int o = 0; o < C8_; ++o) rr += bq[o] * kvreg[o];
    r[b * C_ + t] = rr;
  }
}

// K5: out[b][n][c] = gamma*( sum_c'' x[b][c''][n]*M[c''][c] + r[c] ) + x_flat
// A = x^T (inline transposed scalar loads + pk-cvt), B = Mt rows (bf16 direct).
// grid = B*256 (n-blocks of 64), block 256 = 4 waves; wave w: 16 n-rows x 256 c.
__global__ __launch_bounds__(256) void k5_mfma(const float* __restrict__ x,
                                               const ushort_t* __restrict__ Mt,
                                               const float* __restrict__ r,
                                               const float* __restrict__ gamma_p,
                                               float* __restrict__ out) {
  const int t = threadIdx.x;
  const int lane = t & 63;
  const int w = t >> 6;
  const int b = blockIdx.x >> 8;
  const int n0 = (blockIdx.x & 255) * 64 + w * 16;
  const int l15 = lane & 15, l4 = lane >> 4;
  const floatx4 z = {0.f, 0.f, 0.f, 0.f};
  floatx4 acc[16];
#pragma unroll
  for (int i = 0; i < 16; ++i) acc[i] = z;

  for (int kc = 0; kc < 8; ++kc) {
    const int kb = kc * 32 + l4 * 8;  // c'' base
    const float* xa = x + (size_t)(b * C_ + kb) * N_ + n0 + l15;
    short8 a = pack8(xa[0], xa[(size_t)N_], xa[2 * (size_t)N_], xa[3 * (size_t)N_],
                     xa[4 * (size_t)N_], xa[5 * (size_t)N_], xa[6 * (size_t)N_],
                     xa[7 * (size_t)N_]);
#pragma unroll
    for (int ct = 0; ct < 16; ++ct) {
      short8 bf = *(const short8*)&Mt[(size_t)(b * C_ + ct * 16 + l15) * C_ + kb];
      acc[ct] = __builtin_amdgcn_mfma_f32_16x16x32_bf16(a, bf, acc[ct], 0, 0, 0);
    }
  }
  const float g = gamma_p[0];
#pragma unroll
  for (int ct = 0; ct < 16; ++ct) {
    const int c = ct * 16 + l15;
    const float rv = r[b * C_ + c];
#pragma unroll
    for (int rg = 0; rg < 4; ++rg) {
      const int n = n0 + l4 * 4 + rg;
      const size_t idx = ((size_t)b * N_ + n) * C_ + c;
      out[idx] = g * (acc[ct][rg] + rv) + x[idx];
    }
  }
}

extern "C" void kernel_launch(void* const* d_in, const int* in_sizes, int n_in,
                              void* d_out, int out_size, void* d_ws, size_t ws_size,
                              hipStream_t stream) {
  const float* x  = (const float*)d_in[0];
  const float* Wq = (const float*)d_in[1];
  const float* bq = (const float*)d_in[2];
  const float* Wk = (const float*)d_in[3];
  const float* bk = (const float*)d_in[4];
  const float* Wv = (const float*)d_in[5];
  const float* bv = (const float*)d_in[6];
  const float* gm = (const float*)d_in[7];
  float* out = (float*)d_out;

  float* ws = (float*)d_ws;
  float*    den = ws;                                   // 128
  ushort_t* Wkb = (ushort_t*)(ws + 128);                // 8192 ush = 4096 fl
  ushort_t* p   = (ushort_t*)(ws + 128 + 4096);         // B*32*N ush = 1048576 fl
  float*    kxp = ws + 128 + 4096 + 1048576;            // 2097152 fl
  float*    kx  = kxp + 2097152;                        // 32768
  float*    kv  = kx + 32768;                           // 32768
  ushort_t* Mt  = (ushort_t*)(kv + 32768);              // B*256*256 ush = 131072 fl
  float*    r   = (float*)(kv + 32768 + 131072);        // 1024

  k0_init   <<<32,   256, 0, stream>>>(Wk, Wkb, den);
  k1_p      <<<512,  256, 0, stream>>>(x, Wkb, bk, p, den);
  k3_kxp    <<<256,  256, 0, stream>>>(x, p, kxp);
  k3b_reduce<<<128,  256, 0, stream>>>(kxp, den, kx);
  k4a_kv    <<<128,  256, 0, stream>>>(Wv, bv, kx, kv);
  k4b_M     <<<64,   256, 0, stream>>>(Wq, bq, kv, Mt, r);
  k5_mfma   <<<1024, 256, 0, stream>>>(x, Mt, r, gm, out);
}